// Round 10
// baseline (428.735 us; speedup 1.0000x reference)
//
#include <hip/hip_runtime.h>
#include <hip/hip_bf16.h>
#include <cstddef>

typedef unsigned int  u32;
typedef unsigned short u16;
typedef __attribute__((ext_vector_type(8))) short short8;
typedef __attribute__((ext_vector_type(4))) float f32x4;
typedef __attribute__((ext_vector_type(2))) float f32x2;

#define DV 128
#define DH 128
#define DE 16
#define DO 128
#define PSUB 32   // pooling sub-blocks per graph

// ---------- bf16 helpers (bit tricks, RNE) ----------
__device__ inline float bf_lo(u32 u){ return __uint_as_float(u << 16); }
__device__ inline float bf_hi(u32 u){ return __uint_as_float(u & 0xFFFF0000u); }
__device__ inline u32 fpack2(float a, float b){
  u32 ua = __float_as_uint(a), ub = __float_as_uint(b);
  ua += 0x7FFFu + ((ua >> 16) & 1u);
  ub += 0x7FFFu + ((ub >> 16) & 1u);
  return (ua >> 16) | (ub & 0xFFFF0000u);
}
__device__ inline u16 f2bf(float a){
  u32 ua = __float_as_uint(a); ua += 0x7FFFu + ((ua >> 16) & 1u); return (u16)(ua >> 16);
}

// ---------- fp8 (OCP e4m3) helpers: 4 channels per u32, packed accumulate ----------
__device__ inline void acc_fp8v(u32 s, f32x2& lo, f32x2& hi){
  lo += __builtin_amdgcn_cvt_pk_f32_fp8((int)s, false);   // v_pk_add_f32
  hi += __builtin_amdgcn_cvt_pk_f32_fp8((int)s, true);
}
__device__ inline u32 pack_fp8(float a0, float a1, float a2, float a3){
  int o = __builtin_amdgcn_cvt_pk_fp8_f32(a0, a1, 0, false);
  o = __builtin_amdgcn_cvt_pk_fp8_f32(a2, a3, o, true);
  return (u32)o;
}

// ---------- CSR build ----------
__global__ void k_init(int* cnt, int n){
  int v = blockIdx.x * blockDim.x + threadIdx.x;
  if (v < n) cnt[v] = 0;
}
__global__ void k_count(const int* dst, int* cnt, int* rank, int e2){
  int j = blockIdx.x * blockDim.x + threadIdx.x;
  if (j < e2) rank[j] = atomicAdd(&cnt[dst[j]], 1);
}
// scan of PADDED counts: pc = (cnt+7)&~7  (rows padded to multiple of 8)
__global__ __launch_bounds__(256) void k_scan1(const int* cnt, int* partial, int* bsums, int n){
  __shared__ int lds[256];
  int t = threadIdx.x;
  int base = blockIdx.x * 1024 + t * 4;
  int v0=0,v1=0,v2=0,v3=0;
  if (base + 3 < n){ int4 q = *(const int4*)(cnt + base); v0=q.x; v1=q.y; v2=q.z; v3=q.w; }
  else {
    if (base + 0 < n) v0 = cnt[base];
    if (base + 1 < n) v1 = cnt[base+1];
    if (base + 2 < n) v2 = cnt[base+2];
  }
  v0 = (v0 + 7) & ~7; v1 = (v1 + 7) & ~7; v2 = (v2 + 7) & ~7; v3 = (v3 + 7) & ~7;
  v1 += v0; v2 += v1; v3 += v2;
  lds[t] = v3; __syncthreads();
  for (int off = 1; off < 256; off <<= 1){
    int x = (t >= off) ? lds[t - off] : 0;
    __syncthreads();
    lds[t] += x;
    __syncthreads();
  }
  int add = (t > 0) ? lds[t - 1] : 0;
  if (base + 3 < n){
    int4 q; q.x = v0+add; q.y = v1+add; q.z = v2+add; q.w = v3+add;
    *(int4*)(partial + base) = q;
  } else {
    if (base + 0 < n) partial[base]   = v0 + add;
    if (base + 1 < n) partial[base+1] = v1 + add;
    if (base + 2 < n) partial[base+2] = v2 + add;
  }
  if (t == 255) bsums[blockIdx.x] = lds[255];
}
__global__ void k_scan2(const int* bsums, int* bexc, int nb){
  __shared__ int lds[128];
  int t = threadIdx.x;
  lds[t] = (t < nb) ? bsums[t] : 0;
  __syncthreads();
  for (int off = 1; off < 128; off <<= 1){
    int x = (t >= off) ? lds[t - off] : 0;
    __syncthreads();
    lds[t] += x;
    __syncthreads();
  }
  if (t < nb) bexc[t] = (t > 0) ? lds[t - 1] : 0;
}
// scan3 + prep fused (one fewer launch)
__global__ void k_scan3(const int* partial, const int* bexc, const int* cnt,
                        int* row_ptr, float* dinv, float* degf, int n){
  int i = blockIdx.x * blockDim.x + threadIdx.x;
  if (i < n){
    row_ptr[i + 1] = partial[i] + bexc[i >> 10];
    float c = (float)(cnt[i] + 1);   // in-degree + self-loop
    dinv[i] = rsqrtf(c);
    degf[i] = c;
  }
  if (i == 0) row_ptr[0] = 0;
}
// scatter WITHOUT atomic: pos = row_ptr[dst] + precomputed rank
__global__ void k_scatter(const int* src, const int* dst, const int* rank,
                          const int* row_ptr, int2* ce, int e2){
  int j = blockIdx.x * blockDim.x + threadIdx.x;
  if (j < e2){
    int d = dst[j];
    int pos = row_ptr[d] + rank[j];
    ce[pos] = make_int2(src[j], j);
  }
}
// fill CSR pad slots with {n, 0}; zero the fp8 gather tables' row n (32 u32 each)
__global__ void k_pad(const int* row_ptr, const int* cnt, int2* ce,
                      u32* xws_zrow, u32* h_zrow, int n){
  int v = blockIdx.x * blockDim.x + threadIdx.x;
  if (v < n){
    int s = row_ptr[v] + cnt[v], e = row_ptr[v + 1];
    for (int i = s; i < e; ++i) ce[i] = make_int2(n, 0);
  }
  if (blockIdx.x == 0 && threadIdx.x < 32){
    xws_zrow[threadIdx.x] = 0u;
    h_zrow[threadIdx.x] = 0u;
  }
}

// ---------- fold W_le@W_bot and biases into the h2 GEMM weight (parallel) ----------
__global__ __launch_bounds__(128) void k_wcombo(const float* W_lin, const float* b_lin,
                                                const float* W_le, const float* b_le, float* Wfull){
  int r = blockIdx.x, c = threadIdx.x;
  if (r < DH){
    Wfull[r * DH + c] = W_lin[r * DH + c];
  } else if (r < DH + DE){
    int i = r - DH;
    float acc = 0.f;
    #pragma unroll 8
    for (int k = 0; k < DH; k += 4){
      float4 wl = *(const float4*)(W_le + i * DH + k);
      acc += wl.x * W_lin[(size_t)(DH + k    ) * DH + c];
      acc += wl.y * W_lin[(size_t)(DH + k + 1) * DH + c];
      acc += wl.z * W_lin[(size_t)(DH + k + 2) * DH + c];
      acc += wl.w * W_lin[(size_t)(DH + k + 3) * DH + c];
    }
    Wfull[r * DH + c] = acc;
  } else if (r == 144){
    float acc = b_lin[c];
    #pragma unroll 8
    for (int k = 0; k < DH; k += 4){
      float4 bl = *(const float4*)(b_le + k);
      acc += bl.x * W_lin[(size_t)(DH + k    ) * DH + c];
      acc += bl.y * W_lin[(size_t)(DH + k + 1) * DH + c];
      acc += bl.z * W_lin[(size_t)(DH + k + 2) * DH + c];
      acc += bl.w * W_lin[(size_t)(DH + k + 3) * DH + c];
    }
    Wfull[r * DH + c] = acc;
  } else {
    Wfull[r * DH + c] = 0.f;
  }
}

// ---------- MFMA GEMM (x @ W_gcn only now): [M,128] @ [128,128] -> fp8 rows ----------
template<int K, bool RELU, bool ABF16, bool SCALE, bool OFP8>
__global__ __launch_bounds__(256) void k_gemm_mfma(const void* Ap, const float* W, u32* outb,
                                                   const float* scale, int M){
  constexpr int SA = K + 8;
  constexpr int CS = 136;
  __shared__ u16 Wt[128 * SA];
  __shared__ u16 At[64 * SA];
  int tid = threadIdx.x;
  int row0 = blockIdx.x * 64;
  {
    int c = tid & 127, half = tid >> 7;
    for (int g = half; g < K / 8; g += 2){
      int k0 = g * 8;
      float w0 = W[(size_t)(k0+0)*128 + c], w1 = W[(size_t)(k0+1)*128 + c];
      float w2 = W[(size_t)(k0+2)*128 + c], w3 = W[(size_t)(k0+3)*128 + c];
      float w4 = W[(size_t)(k0+4)*128 + c], w5 = W[(size_t)(k0+5)*128 + c];
      float w6 = W[(size_t)(k0+6)*128 + c], w7 = W[(size_t)(k0+7)*128 + c];
      uint4 pk;
      pk.x = fpack2(w0, w1); pk.y = fpack2(w2, w3);
      pk.z = fpack2(w4, w5); pk.w = fpack2(w6, w7);
      *(uint4*)&Wt[c * SA + k0] = pk;
    }
  }
  constexpr int CH = K / 8;
  for (int idx = tid; idx < 64 * CH; idx += 256){
    int r = idx / CH, ch = idx - r * CH;
    int gr = row0 + r; if (gr > M - 1) gr = M - 1;
    uint4 pk;
    if (ABF16){
      pk = *(const uint4*)((const u16*)Ap + (size_t)gr * K + ch * 8);
    } else {
      const float* A = (const float*)Ap + (size_t)gr * K + ch * 8;
      float4 q0 = *(const float4*)A;
      float4 q1 = *(const float4*)(A + 4);
      pk.x = fpack2(q0.x, q0.y); pk.y = fpack2(q0.z, q0.w);
      pk.z = fpack2(q1.x, q1.y); pk.w = fpack2(q1.z, q1.w);
    }
    *(uint4*)&At[r * SA + ch * 8] = pk;
  }
  __syncthreads();
  int l = tid & 63, w = tid >> 6;
  int m = l & 15, quad = l >> 4;
  f32x4 acc[8];
  #pragma unroll
  for (int ct = 0; ct < 8; ++ct) acc[ct] = (f32x4){0.f, 0.f, 0.f, 0.f};
  #pragma unroll
  for (int ks = 0; ks < K; ks += 32){
    short8 av = *(const short8*)&At[(w * 16 + m) * SA + ks + quad * 8];
    #pragma unroll
    for (int ct = 0; ct < 8; ++ct){
      short8 bv = *(const short8*)&Wt[(ct * 16 + m) * SA + ks + quad * 8];
      acc[ct] = __builtin_amdgcn_mfma_f32_16x16x32_bf16(av, bv, acc[ct], 0, 0, 0);
    }
  }
  __syncthreads();
  u16* Ct = At;
  float sc[4];
  if (SCALE){
    #pragma unroll
    for (int r = 0; r < 4; ++r){
      int gr = row0 + w * 16 + quad * 4 + r;
      sc[r] = scale[gr < M ? gr : (M - 1)];
    }
  }
  #pragma unroll
  for (int ct = 0; ct < 8; ++ct){
    #pragma unroll
    for (int r = 0; r < 4; ++r){
      float vv = acc[ct][r];
      if (SCALE) vv *= sc[r];
      if (RELU)  vv = fmaxf(vv, 0.f);
      Ct[(w * 16 + quad * 4 + r) * CS + ct * 16 + m] = f2bf(vv);
    }
  }
  __syncthreads();
  if (OFP8){
    for (int idx = tid; idx < 64 * 16; idx += 256){
      int r = idx >> 4, c8 = idx & 15;
      int gr = row0 + r;
      if (gr < M){
        uint4 qv = *(const uint4*)&Ct[r * CS + c8 * 8];
        uint2 ov;
        ov.x = (u32)__builtin_amdgcn_cvt_pk_fp8_f32(bf_lo(qv.y), bf_hi(qv.y),
               __builtin_amdgcn_cvt_pk_fp8_f32(bf_lo(qv.x), bf_hi(qv.x), 0, false), true);
        ov.y = (u32)__builtin_amdgcn_cvt_pk_fp8_f32(bf_lo(qv.w), bf_hi(qv.w),
               __builtin_amdgcn_cvt_pk_fp8_f32(bf_lo(qv.z), bf_hi(qv.z), 0, false), true);
        *(uint2*)(outb + (size_t)gr * 32 + c8 * 2) = ov;
      }
    }
  } else {
    for (int idx = tid; idx < 64 * 16; idx += 256){
      int r = idx >> 4, ch = idx & 15;
      int gr = row0 + r;
      if (gr < M){
        uint4 q = *(const uint4*)&Ct[r * CS + ch * 8];
        *(uint4*)(outb + (size_t)gr * 64 + ch * 4) = q;
      }
    }
  }
}

// ---------- phase 1: fp8 table, 2 nodes/wave, pipelined, packed accumulate ----------
__global__ __launch_bounds__(256) void k_phase1(const u32* xws8, const int* row_ptr, const int2* ce,
                                                const float* dinv, const float* b_gcn, u32* h8, int n){
  int lane = threadIdx.x & 63;
  int ln = lane & 31;
  int v = blockIdx.x * 8 + ((threadIdx.x >> 6) << 1) + (lane >> 5);
  if (v >= n) return;
  f32x2 alo = {0.f, 0.f}, ahi = {0.f, 0.f};
  acc_fp8v(xws8[(size_t)v * 32 + ln], alo, ahi);
  int e0 = row_ptr[v], e1 = row_ptr[v + 1];
  int i = e0;
  u32 q0=0,q1=0,q2=0,q3=0,q4=0,q5=0,q6=0,q7=0;
  if (i < e1){
    const int4* cp = (const int4*)(ce + i);
    int4 A = cp[0], B = cp[1], C = cp[2], D = cp[3];
    q0 = xws8[(size_t)A.x * 32 + ln]; q1 = xws8[(size_t)A.z * 32 + ln];
    q2 = xws8[(size_t)B.x * 32 + ln]; q3 = xws8[(size_t)B.z * 32 + ln];
    q4 = xws8[(size_t)C.x * 32 + ln]; q5 = xws8[(size_t)C.z * 32 + ln];
    q6 = xws8[(size_t)D.x * 32 + ln]; q7 = xws8[(size_t)D.z * 32 + ln];
  }
  for (; i + 8 < e1; i += 8){
    const int4* cp2 = (const int4*)(ce + i + 8);
    int4 A = cp2[0], B = cp2[1], C = cp2[2], D = cp2[3];
    u32 p0 = xws8[(size_t)A.x * 32 + ln], p1 = xws8[(size_t)A.z * 32 + ln];
    u32 p2 = xws8[(size_t)B.x * 32 + ln], p3 = xws8[(size_t)B.z * 32 + ln];
    u32 p4 = xws8[(size_t)C.x * 32 + ln], p5 = xws8[(size_t)C.z * 32 + ln];
    u32 p6 = xws8[(size_t)D.x * 32 + ln], p7 = xws8[(size_t)D.z * 32 + ln];
    acc_fp8v(q0, alo, ahi); acc_fp8v(q1, alo, ahi);
    acc_fp8v(q2, alo, ahi); acc_fp8v(q3, alo, ahi);
    acc_fp8v(q4, alo, ahi); acc_fp8v(q5, alo, ahi);
    acc_fp8v(q6, alo, ahi); acc_fp8v(q7, alo, ahi);
    q0=p0; q1=p1; q2=p2; q3=p3; q4=p4; q5=p5; q6=p6; q7=p7;
  }
  if (i < e1){
    acc_fp8v(q0, alo, ahi); acc_fp8v(q1, alo, ahi);
    acc_fp8v(q2, alo, ahi); acc_fp8v(q3, alo, ahi);
    acc_fp8v(q4, alo, ahi); acc_fp8v(q5, alo, ahi);
    acc_fp8v(q6, alo, ahi); acc_fp8v(q7, alo, ahi);
  }
  float dv = dinv[v];
  float4 bg = *(const float4*)(b_gcn + ln * 4);
  float a0 = fmaxf(fmaf(dv, alo.x, bg.x), 0.f);
  float a1 = fmaxf(fmaf(dv, alo.y, bg.y), 0.f);
  float a2 = fmaxf(fmaf(dv, ahi.x, bg.z), 0.f);
  float a3 = fmaxf(fmaf(dv, ahi.y, bg.w), 0.f);
  h8[(size_t)v * 32 + ln] = pack_fp8(a0, a1, a2, a3);
}

// ---------- FUSED phase 2 + GEMM(160): aggregate 64 nodes into LDS, MFMA, store h2 ----------
// LDS: At 64x168 u16 (21.5 KB) + Wt 128x104 u16 (26.6 KB) = 48 KB -> 3 blocks/CU
__global__ __launch_bounds__(256) void k_phase2g(const u32* h8, const int* row_ptr, const int2* ce,
                                                 const float* edge_attr, const float* degf,
                                                 const float* Wfull, u32* h2b, int n){
  constexpr int SA = 168;   // At row stride (u16): 160 + 8
  constexpr int SW = 104;   // Wt row stride (u16): 96 + 8
  constexpr int CS = 136;   // Ct row stride (u16)
  __shared__ u16 At[64 * SA];
  __shared__ u16 Wt[128 * SW];
  int tid = threadIdx.x;
  int w = tid >> 6;
  int lane = tid & 63;
  int ln = lane & 31, half = lane >> 5;
  int row0 = blockIdx.x * 64;
  int ch = ln & 15, grp = ln >> 4;

  // ---- aggregation: wave w fills At rows w*16 .. w*16+15 (2 nodes at a time) ----
  for (int pair = 0; pair < 8; ++pair){
    int lr = w * 16 + pair * 2 + half;
    int v = row0 + lr;
    u32* rowp = (u32*)&At[lr * SA];
    if (v >= n){
      for (int ii = ln; ii < 80; ii += 32) rowp[ii] = 0u;
      continue;
    }
    f32x2 alo = {0.f, 0.f}, ahi = {0.f, 0.f};
    acc_fp8v(h8[(size_t)v * 32 + ln], alo, ahi);
    float es = 0.f;
    int e0 = row_ptr[v], e1 = row_ptr[v + 1];
    int i = e0;
    u32 q0=0,q1=0,q2=0,q3=0,q4=0,q5=0,q6=0,q7=0;
    int4 A = {0,0,0,0}, B = {0,0,0,0}, C = {0,0,0,0}, D = {0,0,0,0};
    if (i < e1){
      const int4* cp = (const int4*)(ce + i);
      A = cp[0]; B = cp[1]; C = cp[2]; D = cp[3];
      q0 = h8[(size_t)A.x * 32 + ln]; q1 = h8[(size_t)A.z * 32 + ln];
      q2 = h8[(size_t)B.x * 32 + ln]; q3 = h8[(size_t)B.z * 32 + ln];
      q4 = h8[(size_t)C.x * 32 + ln]; q5 = h8[(size_t)C.z * 32 + ln];
      q6 = h8[(size_t)D.x * 32 + ln]; q7 = h8[(size_t)D.z * 32 + ln];
    }
    for (; i + 8 < e1; i += 8){
      const int4* cp2 = (const int4*)(ce + i + 8);
      int4 A2 = cp2[0], B2 = cp2[1], C2 = cp2[2], D2 = cp2[3];
      int s0x = grp ? C.x : A.x, s0y = grp ? C.y : A.y;
      int s1x = grp ? C.z : A.z, s1y = grp ? C.w : A.w;
      int s2x = grp ? D.x : B.x, s2y = grp ? D.y : B.y;
      int s3x = grp ? D.z : B.z, s3y = grp ? D.w : B.w;
      float v0 = edge_attr[(size_t)(s0y >> 1) * DE + ch];
      float v1 = edge_attr[(size_t)(s1y >> 1) * DE + ch];
      float v2 = edge_attr[(size_t)(s2y >> 1) * DE + ch];
      float v3 = edge_attr[(size_t)(s3y >> 1) * DE + ch];
      u32 p0 = h8[(size_t)A2.x * 32 + ln], p1 = h8[(size_t)A2.z * 32 + ln];
      u32 p2 = h8[(size_t)B2.x * 32 + ln], p3 = h8[(size_t)B2.z * 32 + ln];
      u32 p4 = h8[(size_t)C2.x * 32 + ln], p5 = h8[(size_t)C2.z * 32 + ln];
      u32 p6 = h8[(size_t)D2.x * 32 + ln], p7 = h8[(size_t)D2.z * 32 + ln];
      acc_fp8v(q0, alo, ahi); acc_fp8v(q1, alo, ahi);
      acc_fp8v(q2, alo, ahi); acc_fp8v(q3, alo, ahi);
      acc_fp8v(q4, alo, ahi); acc_fp8v(q5, alo, ahi);
      acc_fp8v(q6, alo, ahi); acc_fp8v(q7, alo, ahi);
      es = fmaf((s0x != n) ? 1.f : 0.f, v0, es);
      es = fmaf((s1x != n) ? 1.f : 0.f, v1, es);
      es = fmaf((s2x != n) ? 1.f : 0.f, v2, es);
      es = fmaf((s3x != n) ? 1.f : 0.f, v3, es);
      q0=p0; q1=p1; q2=p2; q3=p3; q4=p4; q5=p5; q6=p6; q7=p7;
      A=A2; B=B2; C=C2; D=D2;
    }
    if (i < e1){
      int s0x = grp ? C.x : A.x, s0y = grp ? C.y : A.y;
      int s1x = grp ? C.z : A.z, s1y = grp ? C.w : A.w;
      int s2x = grp ? D.x : B.x, s2y = grp ? D.y : B.y;
      int s3x = grp ? D.z : B.z, s3y = grp ? D.w : B.w;
      float v0 = edge_attr[(size_t)(s0y >> 1) * DE + ch];
      float v1 = edge_attr[(size_t)(s1y >> 1) * DE + ch];
      float v2 = edge_attr[(size_t)(s2y >> 1) * DE + ch];
      float v3 = edge_attr[(size_t)(s3y >> 1) * DE + ch];
      acc_fp8v(q0, alo, ahi); acc_fp8v(q1, alo, ahi);
      acc_fp8v(q2, alo, ahi); acc_fp8v(q3, alo, ahi);
      acc_fp8v(q4, alo, ahi); acc_fp8v(q5, alo, ahi);
      acc_fp8v(q6, alo, ahi); acc_fp8v(q7, alo, ahi);
      es = fmaf((s0x != n) ? 1.f : 0.f, v0, es);
      es = fmaf((s1x != n) ? 1.f : 0.f, v1, es);
      es = fmaf((s2x != n) ? 1.f : 0.f, v2, es);
      es = fmaf((s3x != n) ? 1.f : 0.f, v3, es);
    }
    es += __shfl_xor(es, 16);
    float c0v = __shfl(es, half * 32 + (ln & 7) * 2);
    float c1v = __shfl(es, half * 32 + (ln & 7) * 2 + 1);
    uint2 o; o.x = fpack2(alo.x, alo.y); o.y = fpack2(ahi.x, ahi.y);
    *(uint2*)(rowp + ln * 2) = o;
    if (ln < 8){
      rowp[64 + ln] = fpack2(c0v + 1.0f, c1v + 1.0f);
    } else if (ln < 16){
      rowp[64 + ln] = (ln == 8) ? (u32)f2bf(degf[v]) : 0u;
    }
  }

  // ---- MFMA over K=160 in two Wt chunks (96 + 64) ----
  int m = lane & 15, quad = lane >> 4;
  f32x4 acc[8];
  #pragma unroll
  for (int ct = 0; ct < 8; ++ct) acc[ct] = (f32x4){0.f, 0.f, 0.f, 0.f};
  #pragma unroll
  for (int c = 0; c < 2; ++c){
    int kbase = c ? 96 : 0;
    int klen  = c ? 64 : 96;
    __syncthreads();   // c=0: pre-stage; c=1: all waves done reading chunk-0 Wt
    {
      int col = tid & 127, hf = tid >> 7;
      for (int g = hf; g < klen / 8; g += 2){
        int k0 = kbase + g * 8;
        float w0 = Wfull[(size_t)(k0+0)*128 + col], w1 = Wfull[(size_t)(k0+1)*128 + col];
        float w2 = Wfull[(size_t)(k0+2)*128 + col], w3 = Wfull[(size_t)(k0+3)*128 + col];
        float w4 = Wfull[(size_t)(k0+4)*128 + col], w5 = Wfull[(size_t)(k0+5)*128 + col];
        float w6 = Wfull[(size_t)(k0+6)*128 + col], w7 = Wfull[(size_t)(k0+7)*128 + col];
        uint4 pk;
        pk.x = fpack2(w0, w1); pk.y = fpack2(w2, w3);
        pk.z = fpack2(w4, w5); pk.w = fpack2(w6, w7);
        *(uint4*)&Wt[col * SW + g * 8] = pk;
      }
    }
    __syncthreads();
    for (int ks = 0; ks < klen; ks += 32){
      short8 av = *(const short8*)&At[(w * 16 + m) * SA + kbase + ks + quad * 8];
      #pragma unroll
      for (int ct = 0; ct < 8; ++ct){
        short8 bv = *(const short8*)&Wt[(ct * 16 + m) * SW + ks + quad * 8];
        acc[ct] = __builtin_amdgcn_mfma_f32_16x16x32_bf16(av, bv, acc[ct], 0, 0, 0);
      }
    }
  }
  __syncthreads();   // done with Wt — reuse as Ct

  // ---- epilogue: relu, bf16 pack, coalesced store ----
  u16* Ct = Wt;
  #pragma unroll
  for (int ct = 0; ct < 8; ++ct){
    #pragma unroll
    for (int r = 0; r < 4; ++r){
      float vv = fmaxf(acc[ct][r], 0.f);
      Ct[(w * 16 + quad * 4 + r) * CS + ct * 16 + m] = f2bf(vv);
    }
  }
  __syncthreads();
  for (int idx = tid; idx < 64 * 16; idx += 256){
    int r = idx >> 4, c8 = idx & 15;
    int gr = row0 + r;
    if (gr < n){
      uint4 q = *(const uint4*)&Ct[r * CS + c8 * 8];
      *(uint4*)(h2b + (size_t)gr * 64 + c8 * 4) = q;
    }
  }
}

// ---------- pooling ----------
__global__ void k_starts(const int* batch, int* start, int n, int g){
  int v = blockIdx.x * blockDim.x + threadIdx.x;
  if (v >= n) return;
  int b = batch[v];
  int prev = (v == 0) ? -1 : batch[v - 1];
  for (int q = prev + 1; q <= b; ++q) start[q] = v;
  if (v == n - 1){ for (int q = b + 1; q <= g; ++q) start[q] = n; }
}
__global__ __launch_bounds__(256) void k_pool_a(const u32* h2_b, const int* start, float* partialp){
  __shared__ float2 red[256];
  int g = blockIdx.x >> 5;
  int s = blockIdx.x & (PSUB - 1);
  int s0 = start[g], s1 = start[g + 1];
  int tid = threadIdx.x;
  int cu = tid & 63, rr = tid >> 6;
  float ax = 0.f, ay = 0.f;
  for (int r = s0 + s * 4 + rr; r < s1; r += PSUB * 4){
    u32 q = h2_b[(size_t)r * 64 + cu];
    ax += bf_lo(q); ay += bf_hi(q);
  }
  red[tid] = make_float2(ax, ay);
  __syncthreads();
  if (rr == 0){
    #pragma unroll
    for (int p = 1; p < 4; p++){ float2 o = red[cu + (p << 6)]; ax += o.x; ay += o.y; }
    *(float2*)(partialp + (size_t)blockIdx.x * 128 + cu * 2) = make_float2(ax, ay);
  }
}
__global__ __launch_bounds__(128) void k_poolb_final(const float* partialp, const int* start,
                                                     const float* W_out, const float* b_out,
                                                     float* out){
  __shared__ float pl[DH];
  int g = blockIdx.x, c = threadIdx.x;
  float sum = 0.f;
  #pragma unroll 4
  for (int s = 0; s < PSUB; ++s) sum += partialp[((size_t)g * PSUB + s) * 128 + c];
  int cntg = start[g + 1] - start[g]; if (cntg < 1) cntg = 1;
  pl[c] = sum / (float)cntg;
  __syncthreads();
  float acc = b_out[c];
  for (int k = 0; k < DH; ++k) acc += pl[k] * W_out[k * DO + c];
  out[g * DO + c] = acc;
}

extern "C" void kernel_launch(void* const* d_in, const int* in_sizes, int n_in,
                              void* d_out, int out_size, void* d_ws, size_t ws_size,
                              hipStream_t stream){
  const float* x         = (const float*)d_in[0];
  const int*   edge_index= (const int*)  d_in[1];
  const float* edge_attr = (const float*)d_in[2];
  const int*   batch     = (const int*)  d_in[3];
  const float* W_gcn     = (const float*)d_in[4];
  const float* b_gcn     = (const float*)d_in[5];
  const float* W_le      = (const float*)d_in[6];
  const float* b_le      = (const float*)d_in[7];
  const float* W_lin     = (const float*)d_in[8];
  const float* b_lin     = (const float*)d_in[9];
  const float* W_out     = (const float*)d_in[10];
  const float* b_out     = (const float*)d_in[11];
  float* out = (float*)d_out;

  const int n  = in_sizes[0] / DV;       // 100000
  const int e2 = in_sizes[1] / 2;        // 1600000 directed edges
  const int g  = out_size / DO;          // 64
  const int* srcp = edge_index;
  const int* dstp = edge_index + e2;
  const int e2pad = e2 + 7 * n + 8;      // CSR capacity with per-row pad-to-8

  char* ws = (char*)d_ws;
  size_t off = 0;
  auto alloc = [&](size_t bytes) -> char* {
    char* p = ws + off; off = (off + bytes + 255) & ~(size_t)255; return p;
  };

  int*   cnt     = (int*)  alloc((size_t)n * 4);
  int*   row_ptr = (int*)  alloc((size_t)(n + 1) * 4);
  int*   rank    = (int*)  alloc((size_t)e2 * 4);
  int*   partial = (int*)  alloc((size_t)n * 4);
  int*   bsums   = (int*)  alloc(512);
  int*   bexc    = (int*)  alloc(512);
  float* dinv    = (float*)alloc((size_t)n * 4);
  float* degf    = (float*)alloc((size_t)n * 4);
  int*   startg  = (int*)  alloc((size_t)(g + 1) * 4);
  float* partialp= (float*)alloc((size_t)g * PSUB * 128 * 4);
  float* Wfull   = (float*)alloc(160 * DH * 4);
  u32*   h8      = (u32*)  alloc((size_t)(n + 1) * 128);   // fp8 rows, +1 zero row
  u32*   xws8    = (u32*)  alloc((size_t)(n + 1) * 128);   // fp8 rows, +1 zero row
  int2*  ce      = (int2*) alloc((size_t)e2pad * 8);
  u32*   h2_b    = (u32*)  alloc((size_t)n * 64 * 4);

  const int nb1024 = (n + 1023) / 1024;  // must be <= 128 for k_scan2

  k_init   <<<(n + 255) / 256, 256, 0, stream>>>(cnt, n);
  k_count  <<<(e2 + 255) / 256, 256, 0, stream>>>(dstp, cnt, rank, e2);
  k_scan1  <<<nb1024, 256, 0, stream>>>(cnt, partial, bsums, n);
  k_scan2  <<<1, 128, 0, stream>>>(bsums, bexc, nb1024);
  k_scan3  <<<(n + 255) / 256, 256, 0, stream>>>(partial, bexc, cnt, row_ptr, dinv, degf, n);
  k_scatter<<<(e2 + 255) / 256, 256, 0, stream>>>(srcp, dstp, rank, row_ptr, ce, e2);
  k_pad    <<<(n + 255) / 256, 256, 0, stream>>>(row_ptr, cnt, ce,
                                                 xws8 + (size_t)n * 32, h8 + (size_t)n * 32, n);
  k_wcombo <<<160, 128, 0, stream>>>(W_lin, b_lin, W_le, b_le, Wfull);

  k_gemm_mfma<DV, false, false, true, true><<<(n + 63) / 64, 256, 0, stream>>>(x, W_gcn, xws8, dinv, n);
  k_phase1 <<<(n + 7) / 8, 256, 0, stream>>>(xws8, row_ptr, ce, dinv, b_gcn, h8, n);
  k_phase2g<<<(n + 63) / 64, 256, 0, stream>>>(h8, row_ptr, ce, edge_attr, degf, Wfull, h2_b, n);

  k_starts      <<<(n + 255) / 256, 256, 0, stream>>>(batch, startg, n, g);
  k_pool_a      <<<g * PSUB, 256, 0, stream>>>(h2_b, startg, partialp);
  k_poolb_final <<<g, 128, 0, stream>>>(partialp, startg, W_out, b_out, out);
}